// Round 3
// baseline (228.725 us; speedup 1.0000x reference)
//
#include <hip/hip_runtime.h>
#include <math.h>

// Problem constants
#define NGRID   11
#define NPNT    121     // NGRID*NGRID
#define NFACE   6
#define NHAND   21
#define NPAIR   126     // NHAND*NFACE
#define NCONT   10
#define NBUCKET 256     // fallback atomic-bucket count

__device__ __constant__ int c_face[6][4] = {
    {0,1,2,3},{0,4,2,6},{0,1,4,5},{1,3,5,7},{2,3,6,7},{4,5,6,7}};

__global__ void zero_ws_kernel(float* ws, int n) {
    int t = blockIdx.x * 256 + threadIdx.x;
    if (t < n) ws[t] = 0.0f;
}

// mode 1: direct per-block store at ws[8+2b], counter at ws[0], last block
//         reduces and writes out[0].
// mode 0: atomicAdd into NBUCKET slots (requires zero_ws + finalize_kernel).
__launch_bounds__(128)
__global__ void affinity_kernel(const float* __restrict__ poses,
                                float* __restrict__ ws,
                                float* __restrict__ out,
                                int mode, int slot_mask) {
    const int b = blockIdx.x;
    const int t = threadIdx.x;

    __shared__ float  sh_pose[87];          // 21*3 hand + 8*3 obj
    __shared__ float4 sh_face[NFACE * 6];   // per-face patch vectors + dots
    __shared__ float  sh_d2[NPAIR];
    __shared__ int    sh_pm[NPAIR];
    __shared__ int    sh_ch[NCONT];
    __shared__ float  sh_ctr[NCONT][4];
    __shared__ int    sh_last;
    __shared__ double sh_rn[2], sh_rd[2];

    const float* src = poses + (size_t)b * 87;
    if (t < 87) sh_pose[t] = src[t];
    __syncthreads();

    const float* hand = sh_pose;       // 21 x 3
    const float* obj  = sh_pose + 63;  // 8 x 3

    // ---- per-face patch: p(u,v) = a + b*u + c*v + d*uv
    //   a = C2, b = C3-C2, c = C0-C2, d = C1-C0-C3+C2   (Ck = corner FACE[f][k])
    // plus all pairwise dots needed for the biquadratic q(u,v) = 2h.p - |p|^2
    if (t < NFACE) {
        const int* F = c_face[t];
        float C0[3], C1[3], C2[3], C3[3];
        #pragma unroll
        for (int c = 0; c < 3; ++c) {
            C0[c] = obj[F[0] * 3 + c];
            C1[c] = obj[F[1] * 3 + c];
            C2[c] = obj[F[2] * 3 + c];
            C3[c] = obj[F[3] * 3 + c];
        }
        float av[3], bv[3], cv[3], dv[3];
        #pragma unroll
        for (int c = 0; c < 3; ++c) {
            av[c] = C2[c];
            bv[c] = C3[c] - C2[c];
            cv[c] = C0[c] - C2[c];
            dv[c] = C1[c] - C0[c] - C3[c] + C2[c];
        }
        float aa = 0.f, bb = 0.f, cc = 0.f, dd = 0.f;
        float ab = 0.f, ac = 0.f, ad = 0.f, bc = 0.f, bd = 0.f, cd = 0.f;
        #pragma unroll
        for (int c = 0; c < 3; ++c) {
            aa += av[c] * av[c]; bb += bv[c] * bv[c];
            cc += cv[c] * cv[c]; dd += dv[c] * dv[c];
            ab += av[c] * bv[c]; ac += av[c] * cv[c];
            ad += av[c] * dv[c]; bc += bv[c] * cv[c];
            bd += bv[c] * dv[c]; cd += cv[c] * dv[c];
        }
        sh_face[t * 6 + 0] = make_float4(av[0], av[1], av[2], aa);
        sh_face[t * 6 + 1] = make_float4(bv[0], bv[1], bv[2], bb);
        sh_face[t * 6 + 2] = make_float4(cv[0], cv[1], cv[2], cc);
        sh_face[t * 6 + 3] = make_float4(dv[0], dv[1], dv[2], dd);
        sh_face[t * 6 + 4] = make_float4(2.f * ab, 2.f * ac,
                                         2.f * (ad + bc), 2.f * bd);
        sh_face[t * 6 + 5] = make_float4(2.f * cd, 0.f, 0.f, 0.f);
    }
    __syncthreads();

    // ---- per (hand i, face f): min+argmin of d2 over the 11x11 grid via
    // Horner on the biquadratic q; d2 = xx - q. No LDS in the inner loop.
    if (t < NPAIR) {
        const int i = t / 6;
        const int f = t - i * 6;
        const float hx = hand[i * 3 + 0], hy = hand[i * 3 + 1], hz = hand[i * 3 + 2];
        const float xx  = hx * hx + hy * hy + hz * hz;
        const float hx2 = 2.0f * hx, hy2 = 2.0f * hy, hz2 = 2.0f * hz;

        const float4 F0 = sh_face[f * 6 + 0];
        const float4 F1 = sh_face[f * 6 + 1];
        const float4 F2 = sh_face[f * 6 + 2];
        const float4 F3 = sh_face[f * 6 + 3];
        const float4 F4 = sh_face[f * 6 + 4];
        const float4 F5 = sh_face[f * 6 + 5];

        const float ha2 = fmaf(hx2, F0.x, fmaf(hy2, F0.y, hz2 * F0.z));
        const float hb2 = fmaf(hx2, F1.x, fmaf(hy2, F1.y, hz2 * F1.z));
        const float hc2 = fmaf(hx2, F2.x, fmaf(hy2, F2.y, hz2 * F2.z));
        const float hd2 = fmaf(hx2, F3.x, fmaf(hy2, F3.y, hz2 * F3.z));

        const float C00 = ha2 - F0.w;   // 2h.a - a.a
        const float C10 = hb2 - F4.x;   // 2h.b - 2a.b
        const float C01 = hc2 - F4.y;   // 2h.c - 2a.c
        const float C11 = hd2 - F4.z;   // 2h.d - 2(a.d + b.c)
        const float C20 = -F1.w;        // -b.b
        const float C02 = -F2.w;        // -c.c
        const float C21 = -F4.w;        // -2b.d
        const float C12 = -F5.x;        // -2c.d
        const float C22 = -F3.w;        // -d.d

        const float U[NGRID] = {0.0f, 0.1f, 0.2f, 0.3f, 0.4f, 0.5f,
                                0.6f, 0.7f, 0.8f, 0.9f, 1.0f};
        float qb = -3.0e38f;
        int   bp = 0;
        #pragma unroll
        for (int iu = 0; iu < NGRID; ++iu) {
            const float u  = U[iu];
            const float A2 = fmaf(fmaf(C22, u, C12), u, C02);
            const float A1 = fmaf(fmaf(C21, u, C11), u, C01);
            const float A0 = fmaf(fmaf(C20, u, C10), u, C00);
            #pragma unroll
            for (int iv = 0; iv < NGRID; ++iv) {
                const float v = U[iv];
                const float q = fmaf(fmaf(A2, v, A1), v, A0);
                const int   p = iu * NGRID + iv;
                if (q > qb) { qb = q; bp = p; }  // strict > => first-index argmin
            }
        }
        sh_d2[t] = xx - qb;
        sh_pm[t] = bp;
    }
    __syncthreads();

    // ---- wave 0: select the 10 smallest of the 126 (stable on flat index).
    if (t < 64) {
        float v0 = (t      < NPAIR) ? sh_d2[t]      : 3.0e38f;
        float v1 = (t + 64 < NPAIR) ? sh_d2[t + 64] : 3.0e38f;
        for (int c = 0; c < NCONT; ++c) {
            float bv; int bi;
            if (v1 < v0) { bv = v1; bi = t + 64; } else { bv = v0; bi = t; }
            #pragma unroll
            for (int off = 32; off >= 1; off >>= 1) {
                const float ov = __shfl_xor(bv, off, 64);
                const int   oi = __shfl_xor(bi, off, 64);
                if (ov < bv || (ov == bv && oi < bi)) { bv = ov; bi = oi; }
            }
            if (t == 0) sh_ch[c] = bi;
            if (bi == t)      v0 = 3.0e38f;
            if (bi == t + 64) v1 = 3.0e38f;
        }
    }
    __syncthreads();

    // ---- per-contact exact geometry (threads 0..9): recompute the contact
    // point and distance with the reference arithmetic (f64 grid weights,
    // original bilinear sum, (xx+yy)-2zz+1e-6 formula).
    if (t < NCONT) {
        const int ci = sh_ch[t];
        const int i  = ci / 6;
        const int f  = ci - 6 * i;
        const int p  = sh_pm[ci];
        const int iu = p / NGRID;
        const int iv = p - iu * NGRID;
        const double du = iu * 0.1;
        const double dv = iv * 0.1;
        const float w0 = (float)(dv * (1.0 - du));
        const float w1 = (float)(dv * du);
        const float w2 = (float)((1.0 - dv) * (1.0 - du));
        const float w3 = (float)(du * (1.0 - dv));
        const int i0 = c_face[f][0] * 3, i1 = c_face[f][1] * 3,
                  i2 = c_face[f][2] * 3, i3 = c_face[f][3] * 3;
        const float cx = w0 * obj[i0 + 0] + w1 * obj[i1 + 0]
                       + w2 * obj[i2 + 0] + w3 * obj[i3 + 0];
        const float cy = w0 * obj[i0 + 1] + w1 * obj[i1 + 1]
                       + w2 * obj[i2 + 1] + w3 * obj[i3 + 1];
        const float cz = w0 * obj[i0 + 2] + w1 * obj[i1 + 2]
                       + w2 * obj[i2 + 2] + w3 * obj[i3 + 2];

        const float hx = hand[i * 3 + 0], hy = hand[i * 3 + 1], hz = hand[i * 3 + 2];
        const float xx = hx * hx + hy * hy + hz * hz;
        const float yy = cx * cx + cy * cy + cz * cz;
        const float zz = hx * cx + hy * cy + hz * cz;
        const float dist = sqrtf(((xx + yy) - 2.0f * zz) + 1e-6f);

        float p1x = (((obj[0]  + obj[3])  + obj[6])  + obj[9])  * 0.25f;
        float p1y = (((obj[1]  + obj[4])  + obj[7])  + obj[10]) * 0.25f;
        float p1z = (((obj[2]  + obj[5])  + obj[8])  + obj[11]) * 0.25f;
        float p2x = (((obj[12] + obj[15]) + obj[18]) + obj[21]) * 0.25f;
        float p2y = (((obj[13] + obj[16]) + obj[19]) + obj[22]) * 0.25f;
        float p2z = (((obj[14] + obj[17]) + obj[20]) + obj[23]) * 0.25f;

        float l1 = 0.0f, l2 = 0.0f;
        #pragma unroll
        for (int e = 0; e < 4; ++e) {
            const int a = e, bb2 = (e + 1) & 3;
            {
                const float dx = obj[a * 3 + 0] - obj[bb2 * 3 + 0];
                const float dy = obj[a * 3 + 1] - obj[bb2 * 3 + 1];
                const float dz = obj[a * 3 + 2] - obj[bb2 * 3 + 2];
                l1 += sqrtf(dx * dx + dy * dy + dz * dz);
            }
            {
                const float dx = obj[(a + 4) * 3 + 0] - obj[(bb2 + 4) * 3 + 0];
                const float dy = obj[(a + 4) * 3 + 1] - obj[(bb2 + 4) * 3 + 1];
                const float dz = obj[(a + 4) * 3 + 2] - obj[(bb2 + 4) * 3 + 2];
                l2 += sqrtf(dx * dx + dy * dy + dz * dz);
            }
        }
        l1 *= 0.25f; l2 *= 0.25f;
        const float length = (l1 + l2) * 0.5f;
        const float m = (dist < length * 0.2f) ? 1.0f : 0.0f;

        const float dvx = p2x - p1x, dvy = p2y - p1y, dvz = p2z - p1z;
        const float dvn = sqrtf(dvx * dvx + dvy * dvy + dvz * dvz);
        const float den = dvn + 1e-5f;
        const float ndx = dvx / den, ndy = dvy / den, ndz = dvz / den;
        const float vcx = cx - p1x, vcy = cy - p1y, vcz = cz - p1z;
        const float inner = dvx * vcx + dvy * vcy + dvz * vcz;
        const float tp = inner / den;
        const float rx = p1x + ndx * tp, ry = p1y + ndy * tp, rz = p1z + ndz * tp;
        float nvx = cx - rx, nvy = cy - ry, nvz = cz - rz;
        const float nvn = sqrtf(nvx * nvx + nvy * nvy + nvz * nvz) + 1e-5f;
        nvx /= nvn; nvy /= nvn; nvz /= nvn;

        sh_ctr[t][0] = m * nvx;
        sh_ctr[t][1] = m * nvy;
        sh_ctr[t][2] = m * nvz;
        sh_ctr[t][3] = m;
    }
    __syncthreads();

    // sum(cos_sim*mask) == |sum_c m_c*nv_c|^2 ; mask.sum() == (sum_c m_c)^2
    if (t == 0) {
        float sx = 0.f, sy = 0.f, sz = 0.f, sk = 0.f;
        #pragma unroll
        for (int c = 0; c < NCONT; ++c) {
            sx += sh_ctr[c][0]; sy += sh_ctr[c][1];
            sz += sh_ctr[c][2]; sk += sh_ctr[c][3];
        }
        const float num = sx * sx + sy * sy + sz * sz;
        const float dnm = sk * sk;
        if (mode) {
            ws[8 + 2 * b + 0] = num;
            ws[8 + 2 * b + 1] = dnm;
            __threadfence();                       // release per-block result
            const unsigned old = atomicAdd((unsigned int*)ws, 1u);
            sh_last = (old == gridDim.x - 1u) ? 1 : 0;
        } else {
            float* bucket = ws + 2 * (b & slot_mask);
            atomicAdd(bucket + 0, num);
            atomicAdd(bucket + 1, dnm);
            sh_last = 0;
        }
    }
    __syncthreads();

    // ---- last arriving block reduces everything and writes the scalar.
    if (sh_last) {
        __threadfence();                           // acquire all blocks' stores
        const int nb = (int)gridDim.x;
        const float2* v = (const float2*)(ws + 8);
        double n = 0.0, d = 0.0;
        for (int k = t; k < nb; k += 128) {
            const float2 nd = v[k];
            n += (double)nd.x;
            d += (double)nd.y;
        }
        #pragma unroll
        for (int off = 32; off >= 1; off >>= 1) {
            n += __shfl_xor(n, off, 64);
            d += __shfl_xor(d, off, 64);
        }
        const int w = t >> 6;
        if ((t & 63) == 0) { sh_rn[w] = n; sh_rd[w] = d; }
        __syncthreads();
        if (t == 0) {
            const double nn = sh_rn[0] + sh_rn[1];
            const double dd = sh_rd[0] + sh_rd[1];
            out[0] = (float)(nn / (dd + 1.0));
        }
    }
}

__launch_bounds__(1024)
__global__ void finalize_kernel(const float* __restrict__ ws,
                                float* __restrict__ out, int nslot) {
    const int t = threadIdx.x;
    __shared__ double sh_n[16], sh_d[16];
    double n = 0.0, d = 0.0;
    for (int k = t; k < nslot; k += 1024) {
        n += (double)ws[2 * k + 0];
        d += (double)ws[2 * k + 1];
    }
    #pragma unroll
    for (int off = 32; off >= 1; off >>= 1) {
        n += __shfl_xor(n, off, 64);
        d += __shfl_xor(d, off, 64);
    }
    const int w = t >> 6;
    if ((t & 63) == 0) { sh_n[w] = n; sh_d[w] = d; }
    __syncthreads();
    if (t == 0) {
        double nn = 0.0, dd = 0.0;
        #pragma unroll
        for (int i = 0; i < 16; ++i) { nn += sh_n[i]; dd += sh_d[i]; }
        out[0] = (float)(nn / (dd + 1.0));
    }
}

extern "C" void kernel_launch(void* const* d_in, const int* in_sizes, int n_in,
                              void* d_out, int out_size, void* d_ws, size_t ws_size,
                              hipStream_t stream) {
    const float* poses = (const float*)d_in[0];
    float* out = (float*)d_out;
    float* ws  = (float*)d_ws;
    const int bs = in_sizes[0] / 87;   // 29 keypoints * 3 coords

    const bool direct = (ws_size >= (size_t)(8 + 2 * bs) * sizeof(float));
    if (direct) {
        // counter at ws[0] must start at 0 each call
        hipMemsetAsync(ws, 0, sizeof(unsigned int), stream);
        hipLaunchKernelGGL(affinity_kernel, dim3(bs), dim3(128), 0, stream,
                           poses, ws, out, 1, 0);
    } else {
        hipLaunchKernelGGL(zero_ws_kernel, dim3(1), dim3(256), 0, stream,
                           ws, NBUCKET * 2);
        hipLaunchKernelGGL(affinity_kernel, dim3(bs), dim3(128), 0, stream,
                           poses, ws, out, 0, NBUCKET - 1);
        hipLaunchKernelGGL(finalize_kernel, dim3(1), dim3(1024), 0, stream,
                           ws, out, NBUCKET);
    }
}

// Round 4
// 98.493 us; speedup vs baseline: 2.3222x; 2.3222x over previous
//
#include <hip/hip_runtime.h>
#include <math.h>

// Problem constants
#define NGRID   11
#define NPNT    121     // NGRID*NGRID
#define NFACE   6
#define NHAND   21
#define NPAIR   126     // NHAND*NFACE
#define NCONT   10

// fused-reduction workspace layout (floats)
#define NSUB    64      // sub-counters
#define NBUK    256     // float-pair atomic buckets
#define WS_SUB  16      // word offset of sub-counters
#define WS_BUK  128     // word offset of buckets
#define WS_WORDS (WS_BUK + 2 * NBUK)

#define NBUCKET 256     // fallback path bucket count

__device__ __constant__ int c_face[6][4] = {
    {0,1,2,3},{0,4,2,6},{0,1,4,5},{1,3,5,7},{2,3,6,7},{4,5,6,7}};

__global__ void zero_ws_kernel(float* ws, int n) {
    int t = blockIdx.x * 256 + threadIdx.x;
    if (t < n) ws[t] = 0.0f;
}

// mode 1: fused — float-atomic buckets + hierarchical counters, last block
//         reduces and writes out[0]. Requires ws[0..WS_WORDS) zeroed.
// mode 0: fallback — atomicAdd into NBUCKET slots (zero_ws + finalize_kernel).
__launch_bounds__(128)
__global__ void affinity_kernel(const float* __restrict__ poses,
                                float* __restrict__ ws,
                                float* __restrict__ out,
                                int mode) {
    const int b = blockIdx.x;
    const int t = threadIdx.x;

    __shared__ float  sh_pose[87];          // 21*3 hand + 8*3 obj
    __shared__ float4 sh_face[NFACE * 6];   // per-face patch vectors + dots
    __shared__ float  sh_d2[NPAIR];
    __shared__ int    sh_pm[NPAIR];
    __shared__ int    sh_ch[NCONT];
    __shared__ float  sh_ctr[NCONT][4];
    __shared__ int    sh_last;
    __shared__ double sh_rn[2], sh_rd[2];

    const float* src = poses + (size_t)b * 87;
    if (t < 87) sh_pose[t] = src[t];
    __syncthreads();

    const float* hand = sh_pose;       // 21 x 3
    const float* obj  = sh_pose + 63;  // 8 x 3

    // ---- per-face patch: p(u,v) = a + b*u + c*v + d*uv, plus all pair dots
    // for the biquadratic q(u,v) = 2h.p - |p|^2
    if (t < NFACE) {
        const int* F = c_face[t];
        float C0[3], C1[3], C2[3], C3[3];
        #pragma unroll
        for (int c = 0; c < 3; ++c) {
            C0[c] = obj[F[0] * 3 + c];
            C1[c] = obj[F[1] * 3 + c];
            C2[c] = obj[F[2] * 3 + c];
            C3[c] = obj[F[3] * 3 + c];
        }
        float av[3], bv[3], cv[3], dv[3];
        #pragma unroll
        for (int c = 0; c < 3; ++c) {
            av[c] = C2[c];
            bv[c] = C3[c] - C2[c];
            cv[c] = C0[c] - C2[c];
            dv[c] = C1[c] - C0[c] - C3[c] + C2[c];
        }
        float aa = 0.f, bb = 0.f, cc = 0.f, dd = 0.f;
        float ab = 0.f, ac = 0.f, ad = 0.f, bc = 0.f, bd = 0.f, cd = 0.f;
        #pragma unroll
        for (int c = 0; c < 3; ++c) {
            aa += av[c] * av[c]; bb += bv[c] * bv[c];
            cc += cv[c] * cv[c]; dd += dv[c] * dv[c];
            ab += av[c] * bv[c]; ac += av[c] * cv[c];
            ad += av[c] * dv[c]; bc += bv[c] * cv[c];
            bd += bv[c] * dv[c]; cd += cv[c] * dv[c];
        }
        sh_face[t * 6 + 0] = make_float4(av[0], av[1], av[2], aa);
        sh_face[t * 6 + 1] = make_float4(bv[0], bv[1], bv[2], bb);
        sh_face[t * 6 + 2] = make_float4(cv[0], cv[1], cv[2], cc);
        sh_face[t * 6 + 3] = make_float4(dv[0], dv[1], dv[2], dd);
        sh_face[t * 6 + 4] = make_float4(2.f * ab, 2.f * ac,
                                         2.f * (ad + bc), 2.f * bd);
        sh_face[t * 6 + 5] = make_float4(2.f * cd, 0.f, 0.f, 0.f);
    }
    __syncthreads();

    // ---- per (hand i, face f): min+argmin of d2 over the 11x11 grid.
    // Per-row independent (q,iv) chains for ILP; tree merge keeps exact
    // first-index argmin semantics (strict > keeps earliest row / earliest iv).
    if (t < NPAIR) {
        const int i = t / 6;
        const int f = t - i * 6;
        const float hx = hand[i * 3 + 0], hy = hand[i * 3 + 1], hz = hand[i * 3 + 2];
        const float xx  = hx * hx + hy * hy + hz * hz;
        const float hx2 = 2.0f * hx, hy2 = 2.0f * hy, hz2 = 2.0f * hz;

        const float4 F0 = sh_face[f * 6 + 0];
        const float4 F1 = sh_face[f * 6 + 1];
        const float4 F2 = sh_face[f * 6 + 2];
        const float4 F3 = sh_face[f * 6 + 3];
        const float4 F4 = sh_face[f * 6 + 4];
        const float4 F5 = sh_face[f * 6 + 5];

        const float ha2 = fmaf(hx2, F0.x, fmaf(hy2, F0.y, hz2 * F0.z));
        const float hb2 = fmaf(hx2, F1.x, fmaf(hy2, F1.y, hz2 * F1.z));
        const float hc2 = fmaf(hx2, F2.x, fmaf(hy2, F2.y, hz2 * F2.z));
        const float hd2 = fmaf(hx2, F3.x, fmaf(hy2, F3.y, hz2 * F3.z));

        const float C00 = ha2 - F0.w;
        const float C10 = hb2 - F4.x;
        const float C01 = hc2 - F4.y;
        const float C11 = hd2 - F4.z;
        const float C20 = -F1.w;
        const float C02 = -F2.w;
        const float C21 = -F4.w;
        const float C12 = -F5.x;
        const float C22 = -F3.w;

        const float U[NGRID] = {0.0f, 0.1f, 0.2f, 0.3f, 0.4f, 0.5f,
                                0.6f, 0.7f, 0.8f, 0.9f, 1.0f};
        float rowq[NGRID];
        int   rowv[NGRID];
        #pragma unroll
        for (int iu = 0; iu < NGRID; ++iu) {
            const float u  = U[iu];
            const float A2 = fmaf(fmaf(C22, u, C12), u, C02);
            const float A1 = fmaf(fmaf(C21, u, C11), u, C01);
            const float A0 = fmaf(fmaf(C20, u, C10), u, C00);
            float qr = -3.0e38f;
            int   vb = 0;
            #pragma unroll
            for (int iv = 0; iv < NGRID; ++iv) {
                const float q = fmaf(fmaf(A2, U[iv], A1), U[iv], A0);
                if (q > qr) { qr = q; vb = iv; }   // strict > => earliest iv
            }
            rowq[iu] = qr;
            rowv[iu] = vb;
        }
        float qb = rowq[0];
        int   ru = 0;
        #pragma unroll
        for (int r = 1; r < NGRID; ++r) {
            if (rowq[r] > qb) { qb = rowq[r]; ru = r; }  // strict > => earliest row
        }
        sh_d2[t] = xx - qb;
        sh_pm[t] = ru * NGRID + rowv[ru];
    }
    __syncthreads();

    // ---- wave 0: select the 10 smallest of the 126 (stable on flat index).
    if (t < 64) {
        float v0 = (t      < NPAIR) ? sh_d2[t]      : 3.0e38f;
        float v1 = (t + 64 < NPAIR) ? sh_d2[t + 64] : 3.0e38f;
        for (int c = 0; c < NCONT; ++c) {
            float bv; int bi;
            if (v1 < v0) { bv = v1; bi = t + 64; } else { bv = v0; bi = t; }
            #pragma unroll
            for (int off = 32; off >= 1; off >>= 1) {
                const float ov = __shfl_xor(bv, off, 64);
                const int   oi = __shfl_xor(bi, off, 64);
                if (ov < bv || (ov == bv && oi < bi)) { bv = ov; bi = oi; }
            }
            if (t == 0) sh_ch[c] = bi;
            if (bi == t)      v0 = 3.0e38f;
            if (bi == t + 64) v1 = 3.0e38f;
        }
    }
    __syncthreads();

    // ---- per-contact exact geometry (threads 0..9): reference arithmetic
    // (f64 grid weights, original bilinear sum, (xx+yy)-2zz+1e-6 formula).
    if (t < NCONT) {
        const int ci = sh_ch[t];
        const int i  = ci / 6;
        const int f  = ci - 6 * i;
        const int p  = sh_pm[ci];
        const int iu = p / NGRID;
        const int iv = p - iu * NGRID;
        const double du = iu * 0.1;
        const double dv = iv * 0.1;
        const float w0 = (float)(dv * (1.0 - du));
        const float w1 = (float)(dv * du);
        const float w2 = (float)((1.0 - dv) * (1.0 - du));
        const float w3 = (float)(du * (1.0 - dv));
        const int i0 = c_face[f][0] * 3, i1 = c_face[f][1] * 3,
                  i2 = c_face[f][2] * 3, i3 = c_face[f][3] * 3;
        const float cx = w0 * obj[i0 + 0] + w1 * obj[i1 + 0]
                       + w2 * obj[i2 + 0] + w3 * obj[i3 + 0];
        const float cy = w0 * obj[i0 + 1] + w1 * obj[i1 + 1]
                       + w2 * obj[i2 + 1] + w3 * obj[i3 + 1];
        const float cz = w0 * obj[i0 + 2] + w1 * obj[i1 + 2]
                       + w2 * obj[i2 + 2] + w3 * obj[i3 + 2];

        const float hx = hand[i * 3 + 0], hy = hand[i * 3 + 1], hz = hand[i * 3 + 2];
        const float xx = hx * hx + hy * hy + hz * hz;
        const float yy = cx * cx + cy * cy + cz * cz;
        const float zz = hx * cx + hy * cy + hz * cz;
        const float dist = sqrtf(((xx + yy) - 2.0f * zz) + 1e-6f);

        float p1x = (((obj[0]  + obj[3])  + obj[6])  + obj[9])  * 0.25f;
        float p1y = (((obj[1]  + obj[4])  + obj[7])  + obj[10]) * 0.25f;
        float p1z = (((obj[2]  + obj[5])  + obj[8])  + obj[11]) * 0.25f;
        float p2x = (((obj[12] + obj[15]) + obj[18]) + obj[21]) * 0.25f;
        float p2y = (((obj[13] + obj[16]) + obj[19]) + obj[22]) * 0.25f;
        float p2z = (((obj[14] + obj[17]) + obj[20]) + obj[23]) * 0.25f;

        float l1 = 0.0f, l2 = 0.0f;
        #pragma unroll
        for (int e = 0; e < 4; ++e) {
            const int a = e, bb2 = (e + 1) & 3;
            {
                const float dx = obj[a * 3 + 0] - obj[bb2 * 3 + 0];
                const float dy = obj[a * 3 + 1] - obj[bb2 * 3 + 1];
                const float dz = obj[a * 3 + 2] - obj[bb2 * 3 + 2];
                l1 += sqrtf(dx * dx + dy * dy + dz * dz);
            }
            {
                const float dx = obj[(a + 4) * 3 + 0] - obj[(bb2 + 4) * 3 + 0];
                const float dy = obj[(a + 4) * 3 + 1] - obj[(bb2 + 4) * 3 + 1];
                const float dz = obj[(a + 4) * 3 + 2] - obj[(bb2 + 4) * 3 + 2];
                l2 += sqrtf(dx * dx + dy * dy + dz * dz);
            }
        }
        l1 *= 0.25f; l2 *= 0.25f;
        const float length = (l1 + l2) * 0.5f;
        const float m = (dist < length * 0.2f) ? 1.0f : 0.0f;

        const float dvx = p2x - p1x, dvy = p2y - p1y, dvz = p2z - p1z;
        const float dvn = sqrtf(dvx * dvx + dvy * dvy + dvz * dvz);
        const float den = dvn + 1e-5f;
        const float ndx = dvx / den, ndy = dvy / den, ndz = dvz / den;
        const float vcx = cx - p1x, vcy = cy - p1y, vcz = cz - p1z;
        const float inner = dvx * vcx + dvy * vcy + dvz * vcz;
        const float tp = inner / den;
        const float rx = p1x + ndx * tp, ry = p1y + ndy * tp, rz = p1z + ndz * tp;
        float nvx = cx - rx, nvy = cy - ry, nvz = cz - rz;
        const float nvn = sqrtf(nvx * nvx + nvy * nvy + nvz * nvz) + 1e-5f;
        nvx /= nvn; nvy /= nvn; nvz /= nvn;

        sh_ctr[t][0] = m * nvx;
        sh_ctr[t][1] = m * nvy;
        sh_ctr[t][2] = m * nvz;
        sh_ctr[t][3] = m;
    }
    __syncthreads();

    // sum(cos_sim*mask) == |sum_c m_c*nv_c|^2 ; mask.sum() == (sum_c m_c)^2
    if (t == 0) {
        float sx = 0.f, sy = 0.f, sz = 0.f, sk = 0.f;
        #pragma unroll
        for (int c = 0; c < NCONT; ++c) {
            sx += sh_ctr[c][0]; sy += sh_ctr[c][1];
            sz += sh_ctr[c][2]; sk += sh_ctr[c][3];
        }
        const float num = sx * sx + sy * sy + sz * sz;
        const float dnm = sk * sk;
        sh_last = 0;
        if (mode) {
            // ---- fence-free fused reduction: ALL cross-block traffic is
            // atomics (coherent point) — no __threadfence / no L2 writeback.
            float* bkt = ws + WS_BUK + 2 * (b & (NBUK - 1));
            const float r0 = atomicAdd(bkt + 0, num);
            const float r1 = atomicAdd(bkt + 1, dnm);
            // Consume returns: HW vmcnt dependency => bucket adds completed
            // at the coherent point before anything below issues.
            asm volatile("" :: "v"(r0), "v"(r1) : "memory");
            unsigned* subs = (unsigned*)ws + WS_SUB;
            const unsigned nb = gridDim.x;
            const unsigned g  = (unsigned)b & (NSUB - 1);
            const unsigned quota = (nb - 1u - g) / NSUB + 1u; // blocks in group g
            const unsigned old = atomicAdd(subs + g, 1u);
            if (old + 1u == quota) {          // last of this group (dep on old)
                const unsigned ngroups = nb < NSUB ? nb : NSUB;
                const unsigned m2 = atomicAdd((unsigned*)ws, 1u);
                if (m2 + 1u == ngroups) sh_last = 1;
            }
        } else {
            float* bucket = ws + 2 * (b & (NBUCKET - 1));
            atomicAdd(bucket + 0, num);
            atomicAdd(bucket + 1, dnm);
        }
    }
    __syncthreads();

    // ---- globally-last block: reduce buckets via atomic-RMW reads
    // (coherent-point reads — immune to stale per-XCD L2 lines).
    if (sh_last) {
        double n = 0.0, d = 0.0;
        for (int k = t; k < NBUK; k += 128) {
            float* bkt = ws + WS_BUK + 2 * k;
            n += (double)atomicAdd(bkt + 0, 0.0f);
            d += (double)atomicAdd(bkt + 1, 0.0f);
        }
        #pragma unroll
        for (int off = 32; off >= 1; off >>= 1) {
            n += __shfl_xor(n, off, 64);
            d += __shfl_xor(d, off, 64);
        }
        const int w = t >> 6;
        if ((t & 63) == 0) { sh_rn[w] = n; sh_rd[w] = d; }
        __syncthreads();
        if (t == 0) {
            const double nn = sh_rn[0] + sh_rn[1];
            const double dd = sh_rd[0] + sh_rd[1];
            out[0] = (float)(nn / (dd + 1.0));
        }
    }
}

__launch_bounds__(1024)
__global__ void finalize_kernel(const float* __restrict__ ws,
                                float* __restrict__ out, int nslot) {
    const int t = threadIdx.x;
    __shared__ double sh_n[16], sh_d[16];
    double n = 0.0, d = 0.0;
    for (int k = t; k < nslot; k += 1024) {
        n += (double)ws[2 * k + 0];
        d += (double)ws[2 * k + 1];
    }
    #pragma unroll
    for (int off = 32; off >= 1; off >>= 1) {
        n += __shfl_xor(n, off, 64);
        d += __shfl_xor(d, off, 64);
    }
    const int w = t >> 6;
    if ((t & 63) == 0) { sh_n[w] = n; sh_d[w] = d; }
    __syncthreads();
    if (t == 0) {
        double nn = 0.0, dd = 0.0;
        #pragma unroll
        for (int i = 0; i < 16; ++i) { nn += sh_n[i]; dd += sh_d[i]; }
        out[0] = (float)(nn / (dd + 1.0));
    }
}

extern "C" void kernel_launch(void* const* d_in, const int* in_sizes, int n_in,
                              void* d_out, int out_size, void* d_ws, size_t ws_size,
                              hipStream_t stream) {
    const float* poses = (const float*)d_in[0];
    float* out = (float*)d_out;
    float* ws  = (float*)d_ws;
    const int bs = in_sizes[0] / 87;   // 29 keypoints * 3 coords

    if (ws_size >= (size_t)WS_WORDS * sizeof(float)) {
        hipMemsetAsync(ws, 0, WS_WORDS * sizeof(float), stream);
        hipLaunchKernelGGL(affinity_kernel, dim3(bs), dim3(128), 0, stream,
                           poses, ws, out, 1);
    } else {
        hipLaunchKernelGGL(zero_ws_kernel, dim3(1), dim3(256), 0, stream,
                           ws, NBUCKET * 2);
        hipLaunchKernelGGL(affinity_kernel, dim3(bs), dim3(128), 0, stream,
                           poses, ws, out, 0);
        hipLaunchKernelGGL(finalize_kernel, dim3(1), dim3(1024), 0, stream,
                           ws, out, NBUCKET);
    }
}

// Round 5
// 82.580 us; speedup vs baseline: 2.7697x; 1.1927x over previous
//
#include <hip/hip_runtime.h>
#include <math.h>

// Problem constants
#define NGRID   11
#define NPAIR   126     // 21 hand kp * 6 faces
#define NCONT   10

// fused-reduction workspace layout (floats)
#define NSUB    64      // sub-counters
#define NBUK    128     // float-pair atomic buckets
#define WS_SUB  16      // word offset of sub-counters
#define WS_BUK  128     // word offset of buckets
#define WS_WORDS (WS_BUK + 2 * NBUK)   // 384 words

#define NBUCKET 256     // fallback path bucket count

__device__ __constant__ int4 c_face4[6] = {
    {0,1,2,3},{0,4,2,6},{0,1,4,5},{1,3,5,7},{2,3,6,7},{4,5,6,7}};
// exact f32 images of np.linspace(0,1,11) (f64) — same literals as the scan
__device__ __constant__ float c_U[NGRID] = {
    0.0f,0.1f,0.2f,0.3f,0.4f,0.5f,0.6f,0.7f,0.8f,0.9f,1.0f};

__global__ void zero_ws_kernel(float* ws, int n) {
    int t = blockIdx.x * 256 + threadIdx.x;
    if (t < n) ws[t] = 0.0f;
}

// Biquadratic coefficients of q(u,v) = 2h.p - |p|^2 over face f's bilinear
// patch p(u,v) = a + b u + c v + d uv. d2 = |h|^2 - q.
__device__ __forceinline__ void pair_coefs(
        const float* __restrict__ obj, float hx, float hy, float hz, int f,
        float& C00, float& C10, float& C01, float& C11,
        float& C20, float& C02, float& C21, float& C12, float& C22) {
    const int4 F = c_face4[f];
    float C0[3], C1[3], C2[3], C3[3];
    #pragma unroll
    for (int c = 0; c < 3; ++c) {
        C0[c] = obj[F.x * 3 + c];
        C1[c] = obj[F.y * 3 + c];
        C2[c] = obj[F.z * 3 + c];
        C3[c] = obj[F.w * 3 + c];
    }
    float av[3], bv[3], cv[3], dv[3];
    #pragma unroll
    for (int c = 0; c < 3; ++c) {
        av[c] = C2[c];
        bv[c] = C3[c] - C2[c];
        cv[c] = C0[c] - C2[c];
        dv[c] = C1[c] - C0[c] - C3[c] + C2[c];
    }
    float aa = 0.f, bb = 0.f, cc = 0.f, dd = 0.f;
    float ab = 0.f, ac = 0.f, ad = 0.f, bc = 0.f, bd = 0.f, cd = 0.f;
    #pragma unroll
    for (int c = 0; c < 3; ++c) {
        aa += av[c] * av[c]; bb += bv[c] * bv[c];
        cc += cv[c] * cv[c]; dd += dv[c] * dv[c];
        ab += av[c] * bv[c]; ac += av[c] * cv[c];
        ad += av[c] * dv[c]; bc += bv[c] * cv[c];
        bd += bv[c] * dv[c]; cd += cv[c] * dv[c];
    }
    const float hx2 = 2.0f * hx, hy2 = 2.0f * hy, hz2 = 2.0f * hz;
    const float ha2 = fmaf(hx2, av[0], fmaf(hy2, av[1], hz2 * av[2]));
    const float hb2 = fmaf(hx2, bv[0], fmaf(hy2, bv[1], hz2 * bv[2]));
    const float hc2 = fmaf(hx2, cv[0], fmaf(hy2, cv[1], hz2 * cv[2]));
    const float hd2 = fmaf(hx2, dv[0], fmaf(hy2, dv[1], hz2 * dv[2]));
    C00 = ha2 - aa;
    C10 = hb2 - 2.f * ab;
    C01 = hc2 - 2.f * ac;
    C11 = hd2 - 2.f * (ad + bc);
    C20 = -bb;  C02 = -cc;  C21 = -2.f * bd;  C12 = -2.f * cd;  C22 = -dd;
}

// 256 threads = 2 batches per block (half = t>>7). Phases:
// load -> scan (row-max + winning row) -> rank-select top-10 -> exact epilogue
// for 10 winners -> per-block atomic combine; globally-last block reduces.
__launch_bounds__(256)
__global__ void affinity_kernel(const float* __restrict__ poses,
                                float* __restrict__ ws,
                                float* __restrict__ out,
                                int bs, int mode) {
    const int t    = threadIdx.x;
    const int half = t >> 7;
    const int t0   = t & 127;
    const int batch = blockIdx.x * 2 + half;
    const bool valid = batch < bs;

    __shared__ float sh_pose[2][88];
    __shared__ __align__(16) unsigned sh_key[2][128];
    __shared__ int   sh_ru[2][128];
    __shared__ int   sh_ch[2][NCONT];
    __shared__ float sh_ctr[2][NCONT][4];
    __shared__ float sh_nd[2][2];
    __shared__ int    sh_last;
    __shared__ double sh_rn[4], sh_rd[4];

    if (valid && t0 < 87) sh_pose[half][t0] = poses[(size_t)batch * 87 + t0];
    __syncthreads();

    const float* hand = sh_pose[half];       // 21 x 3
    const float* obj  = sh_pose[half] + 63;  // 8 x 3

    // ---- scan: per (hand i, face f) thread, max of q over the 11x11 grid
    // (3 ops/point) + winning-row index. Column recovered later by winners.
    if (t0 >= NPAIR) sh_key[half][t0] = 0xFFFFFFFFu;   // pad for uint4 rank reads
    if (valid && t0 < NPAIR) {
        const int i = t0 / 6;
        const int f = t0 - i * 6;
        const float hx = hand[i * 3 + 0], hy = hand[i * 3 + 1], hz = hand[i * 3 + 2];
        const float xx = hx * hx + hy * hy + hz * hz;
        float C00, C10, C01, C11, C20, C02, C21, C12, C22;
        pair_coefs(obj, hx, hy, hz, f, C00, C10, C01, C11, C20, C02, C21, C12, C22);

        const float U[NGRID] = {0.0f,0.1f,0.2f,0.3f,0.4f,0.5f,
                                0.6f,0.7f,0.8f,0.9f,1.0f};
        float qb = -3.0e38f;
        int   ru = 0;
        #pragma unroll
        for (int iu = 0; iu < NGRID; ++iu) {
            const float u  = U[iu];
            const float A2 = fmaf(fmaf(C22, u, C12), u, C02);
            const float A1 = fmaf(fmaf(C21, u, C11), u, C01);
            const float A0 = fmaf(fmaf(C20, u, C10), u, C00);
            float qr = A0;                       // == Horner at v=0 exactly
            #pragma unroll
            for (int iv = 1; iv < NGRID; ++iv) {
                qr = fmaxf(qr, fmaf(fmaf(A2, U[iv], A1), U[iv], A0));
            }
            if (qr > qb) { qb = qr; ru = iu; }   // strict > => earliest row
        }
        float d2 = fmaxf(xx - qb, 0.0f);
        // unique sortable key: truncated d2 bits | pair index (7 LSBs)
        sh_key[half][t0] = (__float_as_uint(d2) & 0xFFFFFF80u) | (unsigned)t0;
        sh_ru[half][t0]  = ru;
    }
    __syncthreads();

    // ---- rank selection: rank_i = #{j : k_j < k_i}; ranks 0..9 = top-10 set
    // (keys unique => exact permutation; broadcast uint4 LDS reads, no chains).
    if (valid && t0 < NPAIR) {
        const unsigned ki = sh_key[half][t0];
        const uint4* kp = (const uint4*)sh_key[half];
        int rank = 0;
        #pragma unroll 8
        for (int j = 0; j < 32; ++j) {
            const uint4 v = kp[j];
            rank += (v.x < ki) + (v.y < ki) + (v.z < ki) + (v.w < ki);
        }
        if (rank < NCONT) sh_ch[half][rank] = t0;
    }
    __syncthreads();

    // ---- exact epilogue for the 10 winners (reference arithmetic: f64 grid
    // weights, original bilinear sum, (xx+yy)-2zz+1e-6 distance).
    if (valid && t0 < NCONT) {
        const int ci = sh_ch[half][t0];
        const int i  = ci / 6;
        const int f  = ci - 6 * i;
        const int ru = sh_ru[half][ci];
        const float hx = hand[i * 3 + 0], hy = hand[i * 3 + 1], hz = hand[i * 3 + 2];

        // recover winning column: re-evaluate row ru bit-identically
        float C00, C10, C01, C11, C20, C02, C21, C12, C22;
        pair_coefs(obj, hx, hy, hz, f, C00, C10, C01, C11, C20, C02, C21, C12, C22);
        const float u  = c_U[ru];                // same literal the scan used
        const float A2 = fmaf(fmaf(C22, u, C12), u, C02);
        const float A1 = fmaf(fmaf(C21, u, C11), u, C01);
        const float A0 = fmaf(fmaf(C20, u, C10), u, C00);
        const float U[NGRID] = {0.0f,0.1f,0.2f,0.3f,0.4f,0.5f,
                                0.6f,0.7f,0.8f,0.9f,1.0f};
        float qr = A0;
        int   vb = 0;
        #pragma unroll
        for (int iv = 1; iv < NGRID; ++iv) {
            const float q = fmaf(fmaf(A2, U[iv], A1), U[iv], A0);
            if (q > qr) { qr = q; vb = iv; }     // strict > => earliest column
        }

        // exact contact point
        const double du = ru * 0.1;
        const double dv = vb * 0.1;
        const float w0 = (float)(dv * (1.0 - du));
        const float w1 = (float)(dv * du);
        const float w2 = (float)((1.0 - dv) * (1.0 - du));
        const float w3 = (float)(du * (1.0 - dv));
        const int4 F = c_face4[f];
        const int i0 = F.x * 3, i1 = F.y * 3, i2 = F.z * 3, i3 = F.w * 3;
        const float cx = w0 * obj[i0 + 0] + w1 * obj[i1 + 0]
                       + w2 * obj[i2 + 0] + w3 * obj[i3 + 0];
        const float cy = w0 * obj[i0 + 1] + w1 * obj[i1 + 1]
                       + w2 * obj[i2 + 1] + w3 * obj[i3 + 1];
        const float cz = w0 * obj[i0 + 2] + w1 * obj[i1 + 2]
                       + w2 * obj[i2 + 2] + w3 * obj[i3 + 2];

        const float xx = hx * hx + hy * hy + hz * hz;
        const float yy = cx * cx + cy * cy + cz * cz;
        const float zz = hx * cx + hy * cy + hz * cz;
        const float dist = sqrtf(((xx + yy) - 2.0f * zz) + 1e-6f);

        float p1x = (((obj[0]  + obj[3])  + obj[6])  + obj[9])  * 0.25f;
        float p1y = (((obj[1]  + obj[4])  + obj[7])  + obj[10]) * 0.25f;
        float p1z = (((obj[2]  + obj[5])  + obj[8])  + obj[11]) * 0.25f;
        float p2x = (((obj[12] + obj[15]) + obj[18]) + obj[21]) * 0.25f;
        float p2y = (((obj[13] + obj[16]) + obj[19]) + obj[22]) * 0.25f;
        float p2z = (((obj[14] + obj[17]) + obj[20]) + obj[23]) * 0.25f;

        float l1 = 0.0f, l2 = 0.0f;
        #pragma unroll
        for (int e = 0; e < 4; ++e) {
            const int a = e, b2 = (e + 1) & 3;
            {
                const float dx = obj[a * 3 + 0] - obj[b2 * 3 + 0];
                const float dy = obj[a * 3 + 1] - obj[b2 * 3 + 1];
                const float dz = obj[a * 3 + 2] - obj[b2 * 3 + 2];
                l1 += sqrtf(dx * dx + dy * dy + dz * dz);
            }
            {
                const float dx = obj[(a + 4) * 3 + 0] - obj[(b2 + 4) * 3 + 0];
                const float dy = obj[(a + 4) * 3 + 1] - obj[(b2 + 4) * 3 + 1];
                const float dz = obj[(a + 4) * 3 + 2] - obj[(b2 + 4) * 3 + 2];
                l2 += sqrtf(dx * dx + dy * dy + dz * dz);
            }
        }
        l1 *= 0.25f; l2 *= 0.25f;
        const float length = (l1 + l2) * 0.5f;
        const float m = (dist < length * 0.2f) ? 1.0f : 0.0f;

        const float dvx = p2x - p1x, dvy = p2y - p1y, dvz = p2z - p1z;
        const float dvn = sqrtf(dvx * dvx + dvy * dvy + dvz * dvz);
        const float den = dvn + 1e-5f;
        const float ndx = dvx / den, ndy = dvy / den, ndz = dvz / den;
        const float vcx = cx - p1x, vcy = cy - p1y, vcz = cz - p1z;
        const float inner = dvx * vcx + dvy * vcy + dvz * vcz;
        const float tp = inner / den;
        const float rx = p1x + ndx * tp, ry = p1y + ndy * tp, rz = p1z + ndz * tp;
        float nvx = cx - rx, nvy = cy - ry, nvz = cz - rz;
        const float nvn = sqrtf(nvx * nvx + nvy * nvy + nvz * nvz) + 1e-5f;
        nvx /= nvn; nvy /= nvn; nvz /= nvn;

        sh_ctr[half][t0][0] = m * nvx;
        sh_ctr[half][t0][1] = m * nvy;
        sh_ctr[half][t0][2] = m * nvz;
        sh_ctr[half][t0][3] = m;
    }
    __syncthreads();

    // ---- per-batch: sum(cos*mask) == |sum m*nv|^2, mask.sum() == (sum m)^2
    if (t0 == 0) {
        float num = 0.f, dnm = 0.f;
        if (valid) {
            float sx = 0.f, sy = 0.f, sz = 0.f, sk = 0.f;
            #pragma unroll
            for (int c = 0; c < NCONT; ++c) {
                sx += sh_ctr[half][c][0]; sy += sh_ctr[half][c][1];
                sz += sh_ctr[half][c][2]; sk += sh_ctr[half][c][3];
            }
            num = sx * sx + sy * sy + sz * sz;
            dnm = sk * sk;
        }
        sh_nd[half][0] = num;
        sh_nd[half][1] = dnm;
    }
    __syncthreads();

    if (t == 0) {
        sh_last = 0;
        const float num = sh_nd[0][0] + sh_nd[1][0];
        const float dnm = sh_nd[0][1] + sh_nd[1][1];
        const int b = blockIdx.x;
        if (mode) {
            // fence-free: all cross-block traffic via atomics (coherent point)
            float* bkt = ws + WS_BUK + 2 * (b & (NBUK - 1));
            const float r0 = atomicAdd(bkt + 0, num);
            const float r1 = atomicAdd(bkt + 1, dnm);
            asm volatile("" :: "v"(r0), "v"(r1) : "memory");  // order via returns
            unsigned* subs = (unsigned*)ws + WS_SUB;
            const unsigned nb = gridDim.x;
            const unsigned g  = (unsigned)b & (NSUB - 1);
            const unsigned quota = (nb - 1u - g) / NSUB + 1u;
            const unsigned old = atomicAdd(subs + g, 1u);
            if (old + 1u == quota) {
                const unsigned ngroups = nb < NSUB ? nb : NSUB;
                const unsigned m2 = atomicAdd((unsigned*)ws, 1u);
                if (m2 + 1u == ngroups) sh_last = 1;
            }
        } else {
            float* bucket = ws + 2 * (b & (NBUCKET - 1));
            atomicAdd(bucket + 0, num);
            atomicAdd(bucket + 1, dnm);
        }
    }
    __syncthreads();

    // ---- globally-last block: reduce buckets via atomic-RMW reads
    if (sh_last) {
        double n = 0.0, d = 0.0;
        if (t < NBUK) {
            float* bkt = ws + WS_BUK + 2 * t;
            n = (double)atomicAdd(bkt + 0, 0.0f);
            d = (double)atomicAdd(bkt + 1, 0.0f);
        }
        #pragma unroll
        for (int off = 32; off >= 1; off >>= 1) {
            n += __shfl_xor(n, off, 64);
            d += __shfl_xor(d, off, 64);
        }
        const int w = t >> 6;
        if ((t & 63) == 0) { sh_rn[w] = n; sh_rd[w] = d; }
        __syncthreads();
        if (t == 0) {
            const double nn = sh_rn[0] + sh_rn[1] + sh_rn[2] + sh_rn[3];
            const double dd = sh_rd[0] + sh_rd[1] + sh_rd[2] + sh_rd[3];
            out[0] = (float)(nn / (dd + 1.0));
        }
    }
}

__launch_bounds__(1024)
__global__ void finalize_kernel(const float* __restrict__ ws,
                                float* __restrict__ out, int nslot) {
    const int t = threadIdx.x;
    __shared__ double sh_n[16], sh_d[16];
    double n = 0.0, d = 0.0;
    for (int k = t; k < nslot; k += 1024) {
        n += (double)ws[2 * k + 0];
        d += (double)ws[2 * k + 1];
    }
    #pragma unroll
    for (int off = 32; off >= 1; off >>= 1) {
        n += __shfl_xor(n, off, 64);
        d += __shfl_xor(d, off, 64);
    }
    const int w = t >> 6;
    if ((t & 63) == 0) { sh_n[w] = n; sh_d[w] = d; }
    __syncthreads();
    if (t == 0) {
        double nn = 0.0, dd = 0.0;
        #pragma unroll
        for (int i = 0; i < 16; ++i) { nn += sh_n[i]; dd += sh_d[i]; }
        out[0] = (float)(nn / (dd + 1.0));
    }
}

extern "C" void kernel_launch(void* const* d_in, const int* in_sizes, int n_in,
                              void* d_out, int out_size, void* d_ws, size_t ws_size,
                              hipStream_t stream) {
    const float* poses = (const float*)d_in[0];
    float* out = (float*)d_out;
    float* ws  = (float*)d_ws;
    const int bs = in_sizes[0] / 87;   // 29 keypoints * 3 coords
    const int nblk = (bs + 1) / 2;     // 2 batches per block

    if (ws_size >= (size_t)WS_WORDS * sizeof(float)) {
        hipMemsetAsync(ws, 0, WS_WORDS * sizeof(float), stream);
        hipLaunchKernelGGL(affinity_kernel, dim3(nblk), dim3(256), 0, stream,
                           poses, ws, out, bs, 1);
    } else {
        hipLaunchKernelGGL(zero_ws_kernel, dim3(1), dim3(256), 0, stream,
                           ws, NBUCKET * 2);
        hipLaunchKernelGGL(affinity_kernel, dim3(nblk), dim3(256), 0, stream,
                           poses, ws, out, bs, 0);
        hipLaunchKernelGGL(finalize_kernel, dim3(1), dim3(1024), 0, stream,
                           ws, out, NBUCKET);
    }
}

// Round 6
// 77.211 us; speedup vs baseline: 2.9623x; 1.0695x over previous
//
#include <hip/hip_runtime.h>
#include <math.h>

// Problem constants
#define NGRID   11
#define NPAIR   126     // 21 hand kp * 6 faces
#define NCONT   10

// fused-reduction workspace layout (floats)
#define NSUB    64
#define NBUK    128
#define WS_SUB  16
#define WS_BUK  128
#define WS_WORDS (WS_BUK + 2 * NBUK)   // 384 words

#define NBUCKET 256     // fallback path bucket count

typedef float v2f __attribute__((ext_vector_type(2)));
#define FMA2(a,b,c) __builtin_elementwise_fma((a),(b),(c))
#define MAX2(a,b)   __builtin_elementwise_max((a),(b))
#define SP2(x)      ((v2f){(x),(x)})

__device__ __constant__ int4 c_face4[6] = {
    {0,1,2,3},{0,4,2,6},{0,1,4,5},{1,3,5,7},{2,3,6,7},{4,5,6,7}};
__device__ __constant__ float c_U[NGRID] = {
    0.0f,0.1f,0.2f,0.3f,0.4f,0.5f,0.6f,0.7f,0.8f,0.9f,1.0f};

__global__ void zero_ws_kernel(float* ws, int n) {
    int t = blockIdx.x * 256 + threadIdx.x;
    if (t < n) ws[t] = 0.0f;
}

// Assemble biquadratic coefficients of q(u,v)=2h.p-|p|^2 from staged face data.
__device__ __forceinline__ void coefs_from_face(
        const float4* __restrict__ Ff, float hx, float hy, float hz,
        float& C00, float& C10, float& C01, float& C11,
        float& C20, float& C02, float& C21, float& C12, float& C22) {
    const float4 F0 = Ff[0], F1 = Ff[1], F2 = Ff[2],
                 F3 = Ff[3], F4 = Ff[4], F5 = Ff[5];
    const float hx2 = 2.0f * hx, hy2 = 2.0f * hy, hz2 = 2.0f * hz;
    const float ha2 = fmaf(hx2, F0.x, fmaf(hy2, F0.y, hz2 * F0.z));
    const float hb2 = fmaf(hx2, F1.x, fmaf(hy2, F1.y, hz2 * F1.z));
    const float hc2 = fmaf(hx2, F2.x, fmaf(hy2, F2.y, hz2 * F2.z));
    const float hd2 = fmaf(hx2, F3.x, fmaf(hy2, F3.y, hz2 * F3.z));
    C00 = ha2 - F0.w;   // 2h.a - a.a
    C10 = hb2 - F4.x;   // 2h.b - 2ab
    C01 = hc2 - F4.y;   // 2h.c - 2ac
    C11 = hd2 - F4.z;   // 2h.d - 2(ad+bc)
    C20 = -F1.w;  C02 = -F2.w;  C21 = -F4.w;  C12 = -F5.x;  C22 = -F3.w;
}

// 256 threads = 2 batches/block (half = t>>7).
// Phases: load -> face-stage+thresholds -> pk-scan (row max + row idx,
// threshold-flag candidates) -> exact partA (contact+dist) on candidates ->
// rank among exact passers -> nv for <=10 winners -> atomic combine.
__launch_bounds__(256)
__global__ void affinity_kernel(const float* __restrict__ poses,
                                float* __restrict__ ws,
                                float* __restrict__ out,
                                int bs, int mode) {
    const int t    = threadIdx.x;
    const int half = t >> 7;
    const int t0   = t & 127;
    const int batch = blockIdx.x * 2 + half;
    const bool valid = batch < bs;

    __shared__ float    sh_pose[2][88];
    __shared__ float4   sh_face[2][36];     // 6 faces x 6 vec4
    __shared__ float    sh_thr[2][2];       // [0]=flag thr on scan d2, [1]=length*0.2
    __shared__ int      sh_ru[2][128];
    __shared__ int      sh_cpair[2][128];
    __shared__ unsigned sh_cnt[2], sh_cnt2[2];
    __shared__ unsigned sh_key[2][128];
    __shared__ float    sh_cont[2][128][3];
    __shared__ float    sh_win[2][NCONT][3];
    __shared__ float    sh_nd[2][2];
    __shared__ int      sh_last;
    __shared__ double   sh_rn[4], sh_rd[4];

    // ---- P0: load pose, zero counters
    if (valid && t0 < 87) sh_pose[half][t0] = poses[(size_t)batch * 87 + t0];
    if (t0 == 127) { sh_cnt[half] = 0u; sh_cnt2[half] = 0u; }
    __syncthreads();

    const float* hand = sh_pose[half];       // 21 x 3
    const float* obj  = sh_pose[half] + 63;  // 8 x 3

    // ---- P1: per-face patch vectors + dots; thresholds
    if (valid && t0 < 6) {
        const int4 F = c_face4[t0];
        float C0[3], C1[3], C2[3], C3[3];
        #pragma unroll
        for (int c = 0; c < 3; ++c) {
            C0[c] = obj[F.x * 3 + c];
            C1[c] = obj[F.y * 3 + c];
            C2[c] = obj[F.z * 3 + c];
            C3[c] = obj[F.w * 3 + c];
        }
        float av[3], bv[3], cv[3], dv[3];
        #pragma unroll
        for (int c = 0; c < 3; ++c) {
            av[c] = C2[c];
            bv[c] = C3[c] - C2[c];
            cv[c] = C0[c] - C2[c];
            dv[c] = C1[c] - C0[c] - C3[c] + C2[c];
        }
        float aa=0.f,bb=0.f,cc=0.f,dd=0.f,ab=0.f,ac=0.f,ad=0.f,bc=0.f,bd=0.f,cd=0.f;
        #pragma unroll
        for (int c = 0; c < 3; ++c) {
            aa += av[c]*av[c]; bb += bv[c]*bv[c];
            cc += cv[c]*cv[c]; dd += dv[c]*dv[c];
            ab += av[c]*bv[c]; ac += av[c]*cv[c];
            ad += av[c]*dv[c]; bc += bv[c]*cv[c];
            bd += bv[c]*dv[c]; cd += cv[c]*dv[c];
        }
        float4* Ff = &sh_face[half][t0 * 6];
        Ff[0] = make_float4(av[0], av[1], av[2], aa);
        Ff[1] = make_float4(bv[0], bv[1], bv[2], bb);
        Ff[2] = make_float4(cv[0], cv[1], cv[2], cc);
        Ff[3] = make_float4(dv[0], dv[1], dv[2], dd);
        Ff[4] = make_float4(2.f*ab, 2.f*ac, 2.f*(ad+bc), 2.f*bd);
        Ff[5] = make_float4(2.f*cd, 0.f, 0.f, 0.f);
    }
    if (valid && t0 == 6) {
        float l1 = 0.0f, l2 = 0.0f;
        #pragma unroll
        for (int e = 0; e < 4; ++e) {
            const int a = e, b2 = (e + 1) & 3;
            {
                const float dx = obj[a*3+0]-obj[b2*3+0];
                const float dy = obj[a*3+1]-obj[b2*3+1];
                const float dz = obj[a*3+2]-obj[b2*3+2];
                l1 += sqrtf(dx*dx + dy*dy + dz*dz);
            }
            {
                const float dx = obj[(a+4)*3+0]-obj[(b2+4)*3+0];
                const float dy = obj[(a+4)*3+1]-obj[(b2+4)*3+1];
                const float dz = obj[(a+4)*3+2]-obj[(b2+4)*3+2];
                l2 += sqrtf(dx*dx + dy*dy + dz*dz);
            }
        }
        l1 *= 0.25f; l2 *= 0.25f;
        const float L02 = (l1 + l2) * 0.5f * 0.2f;
        sh_thr[half][0] = L02 * L02 - 1e-6f + 1e-2f;  // generous flag margin
        sh_thr[half][1] = L02;
    }
    __syncthreads();

    // ---- P2: packed scan — per pair, max of q over the 11x11 grid with
    // winning-row tracking; threshold-flag candidates into compact list.
    if (valid && t0 < NPAIR) {
        const int i = t0 / 6;
        const int f = t0 - i * 6;
        const float hx = hand[i*3+0], hy = hand[i*3+1], hz = hand[i*3+2];
        const float xx = hx*hx + hy*hy + hz*hz;
        float C00,C10,C01,C11,C20,C02,C21,C12,C22;
        coefs_from_face(&sh_face[half][f*6], hx, hy, hz,
                        C00,C10,C01,C11,C20,C02,C21,C12,C22);

        const float U[NGRID] = {0.0f,0.1f,0.2f,0.3f,0.4f,0.5f,
                                0.6f,0.7f,0.8f,0.9f,1.0f};
        float qb = -3.0e38f;
        int   ru = 0;
        // row pairs (0,1)..(8,9) via packed f32; values bit-identical to scalar
        #pragma unroll
        for (int rp = 0; rp < 5; ++rp) {
            const v2f u2 = (v2f){U[2*rp], U[2*rp+1]};
            const v2f A2 = FMA2(FMA2(SP2(C22), u2, SP2(C12)), u2, SP2(C02));
            const v2f A1 = FMA2(FMA2(SP2(C21), u2, SP2(C11)), u2, SP2(C01));
            const v2f A0 = FMA2(FMA2(SP2(C20), u2, SP2(C10)), u2, SP2(C00));
            v2f m2 = A0;                         // Horner at v=0 == A0 exactly
            #pragma unroll
            for (int iv = 1; iv < NGRID; ++iv) {
                const v2f vv = SP2(U[iv]);
                m2 = MAX2(m2, FMA2(FMA2(A2, vv, A1), vv, A0));
            }
            if (m2.x > qb) { qb = m2.x; ru = 2*rp; }     // strict > => earliest
            if (m2.y > qb) { qb = m2.y; ru = 2*rp + 1; }
        }
        {   // row 10 scalar
            const float u = 1.0f;
            const float A2 = fmaf(fmaf(C22,u,C12),u,C02);
            const float A1 = fmaf(fmaf(C21,u,C11),u,C01);
            const float A0 = fmaf(fmaf(C20,u,C10),u,C00);
            float m1 = A0;
            #pragma unroll
            for (int iv = 1; iv < NGRID; ++iv)
                m1 = fmaxf(m1, fmaf(fmaf(A2,U[iv],A1),U[iv],A0));
            if (m1 > qb) { qb = m1; ru = 10; }
        }
        sh_ru[half][t0] = ru;
        const float d2s = xx - qb;
        if (d2s < sh_thr[half][0]) {             // candidate (superset of passers)
            const unsigned s = atomicAdd(&sh_cnt[half], 1u);
            sh_cpair[half][s] = t0;
        }
    }
    __syncthreads();

    // ---- P3: exact partA for candidates — reference arithmetic contact +
    // dist; exact passers get a sortable key + stored contact.
    {
        const int cnt = (int)sh_cnt[half];
        if (t0 < cnt) {
            const int pair = sh_cpair[half][t0];
            const int i  = pair / 6;
            const int f  = pair - 6 * i;
            const int ru = sh_ru[half][pair];
            const float hx = hand[i*3+0], hy = hand[i*3+1], hz = hand[i*3+2];
            float C00,C10,C01,C11,C20,C02,C21,C12,C22;
            coefs_from_face(&sh_face[half][f*6], hx, hy, hz,
                            C00,C10,C01,C11,C20,C02,C21,C12,C22);
            // recover winning column: re-evaluate row ru bit-identically
            const float u  = c_U[ru];
            const float A2 = fmaf(fmaf(C22,u,C12),u,C02);
            const float A1 = fmaf(fmaf(C21,u,C11),u,C01);
            const float A0 = fmaf(fmaf(C20,u,C10),u,C00);
            const float U[NGRID] = {0.0f,0.1f,0.2f,0.3f,0.4f,0.5f,
                                    0.6f,0.7f,0.8f,0.9f,1.0f};
            float qr = A0; int vb = 0;
            #pragma unroll
            for (int iv = 1; iv < NGRID; ++iv) {
                const float q = fmaf(fmaf(A2,U[iv],A1),U[iv],A0);
                if (q > qr) { qr = q; vb = iv; }   // strict > => earliest column
            }
            // exact contact point (f64 grid weights as np.linspace)
            const double du = ru * 0.1;
            const double dv = vb * 0.1;
            const float w0 = (float)(dv * (1.0 - du));
            const float w1 = (float)(dv * du);
            const float w2 = (float)((1.0 - dv) * (1.0 - du));
            const float w3 = (float)(du * (1.0 - dv));
            const int4 F = c_face4[f];
            const int i0 = F.x*3, i1 = F.y*3, i2 = F.z*3, i3 = F.w*3;
            const float cx = w0*obj[i0+0]+w1*obj[i1+0]+w2*obj[i2+0]+w3*obj[i3+0];
            const float cy = w0*obj[i0+1]+w1*obj[i1+1]+w2*obj[i2+1]+w3*obj[i3+1];
            const float cz = w0*obj[i0+2]+w1*obj[i1+2]+w2*obj[i2+2]+w3*obj[i3+2];
            const float xx = hx*hx + hy*hy + hz*hz;
            const float yy = cx*cx + cy*cy + cz*cz;
            const float zz = hx*cx + hy*cy + hz*cz;
            const float d2e = (xx + yy) - 2.0f * zz;
            const float dist = sqrtf(d2e + 1e-6f);
            if (dist < sh_thr[half][1]) {          // exact reference mask test
                const unsigned s2 = atomicAdd(&sh_cnt2[half], 1u);
                const float d2k = fmaxf(d2e, 0.0f);
                sh_key[half][s2] = (__float_as_uint(d2k) & 0xFFFFFF80u)
                                 | (unsigned)pair;
                sh_cont[half][s2][0] = cx;
                sh_cont[half][s2][1] = cy;
                sh_cont[half][s2][2] = cz;
            }
        }
    }
    __syncthreads();

    // ---- P4: rank among exact passers; ranks 0..9 are the reference top-10
    // contributors (passers are strictly below all non-passers).
    const int n2 = (int)sh_cnt2[half];
    if (t0 < n2) {
        const unsigned ke = sh_key[half][t0];
        int rank = 0;
        for (int j = 0; j < n2; ++j) rank += (sh_key[half][j] < ke) ? 1 : 0;
        if (rank < NCONT) {
            sh_win[half][rank][0] = sh_cont[half][t0][0];
            sh_win[half][rank][1] = sh_cont[half][t0][1];
            sh_win[half][rank][2] = sh_cont[half][t0][2];
        }
    }
    __syncthreads();

    // ---- P5: normal vectors for winners (m==1 by construction) + reduce
    const int kwin = n2 < NCONT ? n2 : NCONT;
    float px = 0.f, py = 0.f, pz = 0.f;
    if (valid && t0 < kwin) {
        const float cx = sh_win[half][t0][0];
        const float cy = sh_win[half][t0][1];
        const float cz = sh_win[half][t0][2];
        const float p1x = (((obj[0] +obj[3]) +obj[6]) +obj[9]) *0.25f;
        const float p1y = (((obj[1] +obj[4]) +obj[7]) +obj[10])*0.25f;
        const float p1z = (((obj[2] +obj[5]) +obj[8]) +obj[11])*0.25f;
        const float p2x = (((obj[12]+obj[15])+obj[18])+obj[21])*0.25f;
        const float p2y = (((obj[13]+obj[16])+obj[19])+obj[22])*0.25f;
        const float p2z = (((obj[14]+obj[17])+obj[20])+obj[23])*0.25f;
        const float dvx = p2x-p1x, dvy = p2y-p1y, dvz = p2z-p1z;
        const float dvn = sqrtf(dvx*dvx + dvy*dvy + dvz*dvz);
        const float den = dvn + 1e-5f;
        const float ndx = dvx/den, ndy = dvy/den, ndz = dvz/den;
        const float vcx = cx-p1x, vcy = cy-p1y, vcz = cz-p1z;
        const float inner = dvx*vcx + dvy*vcy + dvz*vcz;
        const float tp = inner / den;
        const float rx = p1x + ndx*tp, ry = p1y + ndy*tp, rz = p1z + ndz*tp;
        float nvx = cx-rx, nvy = cy-ry, nvz = cz-rz;
        const float nvn = sqrtf(nvx*nvx + nvy*nvy + nvz*nvz) + 1e-5f;
        px = nvx / nvn; py = nvy / nvn; pz = nvz / nvn;
    }
    if (t0 < 64) {   // winners live in this wave; reduce over it
        #pragma unroll
        for (int off = 32; off >= 1; off >>= 1) {
            px += __shfl_xor(px, off, 64);
            py += __shfl_xor(py, off, 64);
            pz += __shfl_xor(pz, off, 64);
        }
        if (t0 == 0) {
            sh_nd[half][0] = px*px + py*py + pz*pz;     // |sum m*nv|^2
            sh_nd[half][1] = (float)(kwin * kwin);      // (sum m)^2
        }
    }
    __syncthreads();

    // ---- P6: per-block combine + fence-free global reduction (atomics only)
    if (t == 0) {
        sh_last = 0;
        const float num = sh_nd[0][0] + sh_nd[1][0];
        const float dnm = sh_nd[0][1] + sh_nd[1][1];
        const int b = blockIdx.x;
        if (mode) {
            float* bkt = ws + WS_BUK + 2 * (b & (NBUK - 1));
            const float r0 = atomicAdd(bkt + 0, num);
            const float r1 = atomicAdd(bkt + 1, dnm);
            asm volatile("" :: "v"(r0), "v"(r1) : "memory");  // order via returns
            unsigned* subs = (unsigned*)ws + WS_SUB;
            const unsigned nb = gridDim.x;
            const unsigned g  = (unsigned)b & (NSUB - 1);
            const unsigned quota = (nb - 1u - g) / NSUB + 1u;
            const unsigned old = atomicAdd(subs + g, 1u);
            if (old + 1u == quota) {
                const unsigned ngroups = nb < NSUB ? nb : NSUB;
                const unsigned m2 = atomicAdd((unsigned*)ws, 1u);
                if (m2 + 1u == ngroups) sh_last = 1;
            }
        } else {
            float* bucket = ws + 2 * (b & (NBUCKET - 1));
            atomicAdd(bucket + 0, num);
            atomicAdd(bucket + 1, dnm);
        }
    }
    __syncthreads();

    // ---- globally-last block: reduce buckets via atomic-RMW reads
    if (sh_last) {
        double n = 0.0, d = 0.0;
        if (t < NBUK) {
            float* bkt = ws + WS_BUK + 2 * t;
            n = (double)atomicAdd(bkt + 0, 0.0f);
            d = (double)atomicAdd(bkt + 1, 0.0f);
        }
        #pragma unroll
        for (int off = 32; off >= 1; off >>= 1) {
            n += __shfl_xor(n, off, 64);
            d += __shfl_xor(d, off, 64);
        }
        const int w = t >> 6;
        if ((t & 63) == 0) { sh_rn[w] = n; sh_rd[w] = d; }
        __syncthreads();
        if (t == 0) {
            const double nn = sh_rn[0] + sh_rn[1] + sh_rn[2] + sh_rn[3];
            const double dd = sh_rd[0] + sh_rd[1] + sh_rd[2] + sh_rd[3];
            out[0] = (float)(nn / (dd + 1.0));
        }
    }
}

__launch_bounds__(1024)
__global__ void finalize_kernel(const float* __restrict__ ws,
                                float* __restrict__ out, int nslot) {
    const int t = threadIdx.x;
    __shared__ double sh_n[16], sh_d[16];
    double n = 0.0, d = 0.0;
    for (int k = t; k < nslot; k += 1024) {
        n += (double)ws[2 * k + 0];
        d += (double)ws[2 * k + 1];
    }
    #pragma unroll
    for (int off = 32; off >= 1; off >>= 1) {
        n += __shfl_xor(n, off, 64);
        d += __shfl_xor(d, off, 64);
    }
    const int w = t >> 6;
    if ((t & 63) == 0) { sh_n[w] = n; sh_d[w] = d; }
    __syncthreads();
    if (t == 0) {
        double nn = 0.0, dd = 0.0;
        #pragma unroll
        for (int i = 0; i < 16; ++i) { nn += sh_n[i]; dd += sh_d[i]; }
        out[0] = (float)(nn / (dd + 1.0));
    }
}

extern "C" void kernel_launch(void* const* d_in, const int* in_sizes, int n_in,
                              void* d_out, int out_size, void* d_ws, size_t ws_size,
                              hipStream_t stream) {
    const float* poses = (const float*)d_in[0];
    float* out = (float*)d_out;
    float* ws  = (float*)d_ws;
    const int bs = in_sizes[0] / 87;   // 29 keypoints * 3 coords
    const int nblk = (bs + 1) / 2;     // 2 batches per block

    if (ws_size >= (size_t)WS_WORDS * sizeof(float)) {
        hipMemsetAsync(ws, 0, WS_WORDS * sizeof(float), stream);
        hipLaunchKernelGGL(affinity_kernel, dim3(nblk), dim3(256), 0, stream,
                           poses, ws, out, bs, 1);
    } else {
        hipLaunchKernelGGL(zero_ws_kernel, dim3(1), dim3(256), 0, stream,
                           ws, NBUCKET * 2);
        hipLaunchKernelGGL(affinity_kernel, dim3(nblk), dim3(256), 0, stream,
                           poses, ws, out, bs, 0);
        hipLaunchKernelGGL(finalize_kernel, dim3(1), dim3(1024), 0, stream,
                           ws, out, NBUCKET);
    }
}